// Round 19
// baseline (729.418 us; speedup 1.0000x reference)
//
#include <hip/hip_runtime.h>
#include <hip/hip_bf16.h>

// Problem constants (from reference setup_inputs)
#define N_NODES 16384
#define FM      256
#define NF      (N_NODES * FM)          // 4,194,304 elements per branch tensor
#define NF4     (NF / 4)
#define NPART   8                       // CSR build partitions (~1 per XCD)
#define NSCAN   (NPART * N_NODES)       // 131072 counters per edge set
#define RS_STRIDE 131076                // NSCAN + sentinel + pad
#define NRS_STRIDE (N_NODES + 2)        // node-level row_start stride
#define NCHUNK 128                      // 1024-element chunks in NSCAN
#define NCHUNK_N 16                     // 1024-element chunks in N_NODES

typedef __attribute__((ext_vector_type(8))) short short8;
typedef __attribute__((ext_vector_type(8))) ushort ushort8;
typedef __attribute__((ext_vector_type(4))) float f32x4;

__device__ inline ushort f2bf(float f) {            // fp32 -> bf16 (RNE)
    uint u = __float_as_uint(f);
    return (ushort)((u + 0x7FFFu + ((u >> 16) & 1u)) >> 16);
}
__device__ inline uint pack2bf(float a, float b) {
    return (uint)f2bf(a) | ((uint)f2bf(b) << 16);
}
__device__ inline float bf2f(ushort u) { return __uint_as_float(((uint)u) << 16); }

// ---------------------------------------------------------------------------
// Init: partitioned edge-count histograms = 0, pooled = 0
// ---------------------------------------------------------------------------
__global__ void init_kernel(int* __restrict__ cnt3, float* __restrict__ pooled) {
    int i = blockIdx.x * blockDim.x + threadIdx.x;
    int n = 3 * NSCAN;
    if (i < n) cnt3[i] = 0;
    else if (i < n + 6) pooled[i - n] = 0.0f;
}

// Count histogram keyed by (set, part=blockIdx.x&7, dst): L2-local atomics.
// Edge stream read with non-temporal loads (don't pollute L2 write lines).
__global__ void cnt_edges_all(const int* __restrict__ d0, const int* __restrict__ d1,
                              const int* __restrict__ d2,
                              int* __restrict__ cnt3, int E) {
    int t = blockIdx.y;
    const int* dst = (t == 0) ? d0 : (t == 1) ? d1 : d2;
    int part = blockIdx.x & (NPART - 1);
    int* cnt = cnt3 + t * NSCAN + part * N_NODES;
    int e = blockIdx.x * blockDim.x + threadIdx.x;
    if (e < E) atomicAdd(&cnt[__builtin_nontemporal_load(&dst[e])], 1);
}

// ---------------------------------------------------------------------------
// Hierarchical scans (parallel)
// ---------------------------------------------------------------------------

// tot[set][node] = sum_p cnt[set][p][node]
__global__ void tot_kernel(const int* __restrict__ cnt3, int* __restrict__ tot3) {
    int i = blockIdx.x * blockDim.x + threadIdx.x;     // over 3*N_NODES
    if (i >= 3 * N_NODES) return;
    int set = i / N_NODES;
    int node = i - set * N_NODES;
    const int* cnt = cnt3 + set * NSCAN;
    int s = 0;
#pragma unroll
    for (int p = 0; p < NPART; ++p) s += cnt[p * N_NODES + node];
    tot3[i] = s;
}

// Chunk sums: psum[set][chunk] = sum of src[set][chunk*1024 .. +1024)
__global__ __launch_bounds__(1024) void chunk_sum(const int* __restrict__ src,
                                                  long set_stride,
                                                  int* __restrict__ psum,
                                                  int nchunk) {
    int set = blockIdx.y;
    const int* p = src + (size_t)set * set_stride + (size_t)blockIdx.x * 1024;
    __shared__ int lds[1024];
    int t = threadIdx.x;
    lds[t] = p[t];
    __syncthreads();
    for (int off = 512; off > 0; off >>= 1) {
        if (t < off) lds[t] += lds[t + off];
        __syncthreads();
    }
    if (t == 0) psum[set * nchunk + blockIdx.x] = lds[0];
}

// Scan the chunk sums (3x128 and 3x16) -> exclusive chunk bases. One block.
__global__ __launch_bounds__(128) void scan_chunks(int* __restrict__ psum,
                                                   int* __restrict__ npsum) {
    __shared__ int lds[128];
    int t = threadIdx.x;
    for (int set = 0; set < 3; ++set) {
        int v = psum[set * NCHUNK + t];
        lds[t] = v;
        __syncthreads();
        for (int off = 1; off < 128; off <<= 1) {
            int u = (t >= off) ? lds[t - off] : 0;
            __syncthreads();
            lds[t] += u;
            __syncthreads();
        }
        psum[set * NCHUNK + t] = lds[t] - v;   // exclusive
        __syncthreads();
    }
    for (int set = 0; set < 3; ++set) {
        int v = (t < NCHUNK_N) ? npsum[set * NCHUNK_N + t] : 0;
        lds[t] = v;
        __syncthreads();
        for (int off = 1; off < NCHUNK_N; off <<= 1) {
            int u = (t >= off && t < NCHUNK_N) ? lds[t - off] : 0;
            __syncthreads();
            if (t < NCHUNK_N) lds[t] += u;
            __syncthreads();
        }
        if (t < NCHUNK_N) npsum[set * NCHUNK_N + t] = lds[t] - v;
        __syncthreads();
    }
}

// Final: local 1024-scan + chunk base -> row_start & cursor (partition-major).
__global__ __launch_bounds__(1024) void scan_write_rs(const int* __restrict__ cnt3,
                                                      const int* __restrict__ psum,
                                                      int* __restrict__ rowstart3,
                                                      int* __restrict__ cursor3) {
    int set = blockIdx.y;
    int base = psum[set * NCHUNK + blockIdx.x];
    const int* cnt = cnt3 + set * NSCAN + (size_t)blockIdx.x * 1024;
    int* rs = rowstart3 + set * RS_STRIDE + (size_t)blockIdx.x * 1024;
    int* cur = cursor3 + set * NSCAN + (size_t)blockIdx.x * 1024;
    __shared__ int lds[1024];
    int t = threadIdx.x;
    int v = cnt[t];
    lds[t] = v;
    __syncthreads();
    for (int off = 1; off < 1024; off <<= 1) {
        int u = (t >= off) ? lds[t - off] : 0;
        __syncthreads();
        lds[t] += u;
        __syncthreads();
    }
    int pre = base + lds[t] - v;    // exclusive
    rs[t] = pre;
    cur[t] = pre;
    if (blockIdx.x == NCHUNK - 1 && t == 1023)
        rowstart3[set * RS_STRIDE + NSCAN] = base + lds[t];
}

// Final: local 1024-scan + chunk base -> nodestart (node-major totals).
__global__ __launch_bounds__(1024) void scan_write_nrs(const int* __restrict__ tot3,
                                                       const int* __restrict__ npsum,
                                                       int* __restrict__ nodestart3) {
    int set = blockIdx.y;
    int base = npsum[set * NCHUNK_N + blockIdx.x];
    const int* tot = tot3 + (size_t)set * N_NODES + (size_t)blockIdx.x * 1024;
    int* nrs = nodestart3 + set * NRS_STRIDE + (size_t)blockIdx.x * 1024;
    __shared__ int lds[1024];
    int t = threadIdx.x;
    int v = tot[t];
    lds[t] = v;
    __syncthreads();
    for (int off = 1; off < 1024; off <<= 1) {
        int u = (t >= off) ? lds[t - off] : 0;
        __syncthreads();
        lds[t] += u;
        __syncthreads();
    }
    nrs[t] = base + lds[t] - v;     // exclusive
    if (blockIdx.x == NCHUNK_N - 1 && t == 1023)
        nodestart3[set * NRS_STRIDE + N_NODES] = base + lds[t];
}

// Scatter edges into partitioned CSR slots as packed {src, raw weight bits}.
// Edge/weight streams read non-temporally (protect L2 CSR write lines).
__global__ void scatter_all(const int* __restrict__ s0, const int* __restrict__ s1,
                            const int* __restrict__ s2,
                            const float* __restrict__ e0, const float* __restrict__ e1,
                            const float* __restrict__ e2,
                            int* __restrict__ cursor3, int2* __restrict__ csr3, int E) {
    int t = blockIdx.y;
    const int* ed = (t == 0) ? s0 : (t == 1) ? s1 : s2;   // [2][E]: src row, dst row
    const float* ew = (t == 0) ? e0 : (t == 1) ? e1 : e2;
    int part = blockIdx.x & (NPART - 1);
    int* cursor = cursor3 + t * NSCAN + part * N_NODES;
    int2* csr = csr3 + (size_t)t * E;
    int e = blockIdx.x * blockDim.x + threadIdx.x;
    if (e >= E) return;
    int s = __builtin_nontemporal_load(&ed[e]);
    int d = __builtin_nontemporal_load(&ed[E + e]);
    float w = __builtin_nontemporal_load(&ew[e]);
    int pos = atomicAdd(&cursor[d], 1);
    csr[pos] = make_int2(s, __float_as_int(w));
}

// deg[d] = 1 + sum of row weights over the 8 partition segments; dinv=rsqrt.
__global__ __launch_bounds__(256) void deg_dinv_all(const int2* __restrict__ csr3,
                                                    const int* __restrict__ rowstart3,
                                                    float* __restrict__ dinv3, int E) {
    int t = blockIdx.y;
    const int2* csr = csr3 + (size_t)t * E;
    const int* rs = rowstart3 + t * RS_STRIDE;
    int node = blockIdx.x * 4 + (threadIdx.x >> 6);
    int lane = threadIdx.x & 63;
    int p = lane >> 3;
    int l8 = lane & 7;
    int beg = rs[p * N_NODES + node], end = rs[p * N_NODES + node + 1];
    float s = 0.0f;
    for (int j = beg + l8; j < end; j += 8)
        s += __int_as_float(csr[j].y);
    for (int o = 32; o > 0; o >>= 1) s += __shfl_down(s, o);
    if (lane == 0) dinv3[t * N_NODES + node] = rsqrtf(1.0f + s);
}

// Compact partitioned CSR -> contiguous csr_src[] + csr_norm[] with the FULL
// norm = w * dinv[src] * dinv[dst].
__global__ __launch_bounds__(256) void compact_norm_all(const int2* __restrict__ csr3,
                                                        const int* __restrict__ rowstart3,
                                                        const int* __restrict__ nodestart3,
                                                        const float* __restrict__ dinv3,
                                                        int* __restrict__ csrsrc3,
                                                        float* __restrict__ csrnorm3,
                                                        int E) {
    int t = blockIdx.y;
    const int2* src = csr3 + (size_t)t * E;
    const int* prs = rowstart3 + t * RS_STRIDE;
    const int* nrs = nodestart3 + t * NRS_STRIDE;
    const float* dinv = dinv3 + t * N_NODES;
    int* dsrc = csrsrc3 + (size_t)t * E;
    float* dnorm = csrnorm3 + (size_t)t * E;
    int node = blockIdx.x * 4 + (threadIdx.x >> 6);
    int lane = threadIdx.x & 63;
    float din = dinv[node];
    int w = nrs[node];
#pragma unroll
    for (int p = 0; p < NPART; ++p) {
        int beg = prs[p * N_NODES + node];
        int end = prs[p * N_NODES + node + 1];
        for (int j = beg + lane; j < end; j += 64) {
            int2 c = src[j];
            dsrc[w + (j - beg)] = c.x;
            dnorm[w + (j - beg)] = __int_as_float(c.y) * dinv[c.x] * din;
        }
        w += end - beg;
    }
}

// ---------------------------------------------------------------------------
// Weight pre-pack: WT[n][k] = bf16(W[k][n]) for all 6 weights (grid.z = widx).
// ---------------------------------------------------------------------------
__global__ __launch_bounds__(256) void wpack_kernel(const float* __restrict__ w0,
                                                    const float* __restrict__ w1,
                                                    const float* __restrict__ w2,
                                                    const float* __restrict__ w3,
                                                    const float* __restrict__ w4,
                                                    const float* __restrict__ w5,
                                                    ushort* __restrict__ wt) {
    const float* W;
    switch (blockIdx.z) {
        case 0: W = w0; break; case 1: W = w1; break; case 2: W = w2; break;
        case 3: W = w3; break; case 4: W = w4; break; default: W = w5; break;
    }
    __shared__ float tl[16][17];
    int tx = threadIdx.x & 15, ty = threadIdx.x >> 4;
    int k0 = blockIdx.x * 16, n0 = blockIdx.y * 16;
    tl[ty][tx] = W[(size_t)(k0 + ty) * FM + n0 + tx];
    __syncthreads();
    wt[(size_t)blockIdx.z * FM * FM + (size_t)(n0 + ty) * FM + k0 + tx] = f2bf(tl[tx][ty]);
}

// x (fp32) -> bf16 once; reused as GEMM A input by the 3 first-layer convs.
__global__ void x2bf_kernel(const float* __restrict__ x, ushort* __restrict__ xb) {
    int i = blockIdx.x * blockDim.x + threadIdx.x;   // over NF/8
    if (i >= NF / 8) return;
    const float4* xp = (const float4*)x;
    float4 a = xp[2 * i], b = xp[2 * i + 1];
    uint4 pk;
    pk.x = pack2bf(a.x, a.y);
    pk.y = pack2bf(a.z, a.w);
    pk.z = pack2bf(b.x, b.y);
    pk.w = pack2bf(b.z, b.w);
    ((uint4*)xb)[i] = pk;
}

// ---------------------------------------------------------------------------
// bf16 MFMA GEMM: C_bf16[M,256] = A_bf16[M,256] @ W (WT[n][k] bf16).
// BM=128, BN=64, BK=64; 4 waves (2x2); A staged to XOR-swizzled LDS (copy).
// ---------------------------------------------------------------------------
__global__ __launch_bounds__(256) void gemm_mfma(const ushort* __restrict__ A,
                                                 const ushort* __restrict__ WT,
                                                 ushort* __restrict__ C) {
    __shared__ ushort A_lds[128 * 64];

    const int tid = threadIdx.x;
    const int lane = tid & 63;
    const int wid = tid >> 6;
    const int wm = wid >> 1, wn = wid & 1;
    const int bm = blockIdx.x * 128;
    const int bn = blockIdx.y * 64;
    const int l15 = lane & 15;
    const int lg = lane >> 4;

    f32x4 acc[4][2];
#pragma unroll
    for (int i = 0; i < 4; ++i)
#pragma unroll
        for (int n = 0; n < 2; ++n) acc[i][n] = (f32x4){0.f, 0.f, 0.f, 0.f};

    const int srow = tid >> 1;
    const int shk = tid & 1;
    const ushort* arow_p = &A[(size_t)(bm + srow) * FM + shk * 32];

    for (int k0 = 0; k0 < 256; k0 += 64) {
        {
            const ushort* ap = arow_p + k0;
#pragma unroll
            for (int g = 0; g < 4; ++g) {
                ushort8 v = *(const ushort8*)(ap + g * 8);
                int kk = shk * 32 + g * 8;
                int idx = srow * 64 + (kk ^ ((srow & 7) << 3));
                *(ushort8*)&A_lds[idx] = v;
            }
        }
        __syncthreads();
#pragma unroll
        for (int s = 0; s < 2; ++s) {
            short8 bfrag[2];
#pragma unroll
            for (int n = 0; n < 2; ++n) {
                int col = bn + wn * 32 + n * 16 + l15;
                bfrag[n] = *(const short8*)&WT[(size_t)col * FM + k0 + s * 32 + lg * 8];
            }
#pragma unroll
            for (int i = 0; i < 4; ++i) {
                int row = wm * 64 + i * 16 + l15;
                int kk = s * 32 + lg * 8;
                short8 afrag = *(const short8*)&A_lds[row * 64 + (kk ^ ((row & 7) << 3))];
#pragma unroll
                for (int n = 0; n < 2; ++n)
                    acc[i][n] = __builtin_amdgcn_mfma_f32_16x16x32_bf16(
                        afrag, bfrag[n], acc[i][n], 0, 0, 0);
            }
        }
        __syncthreads();
    }
#pragma unroll
    for (int i = 0; i < 4; ++i) {
#pragma unroll
        for (int n = 0; n < 2; ++n) {
            int col = bn + wn * 32 + n * 16 + l15;
#pragma unroll
            for (int r = 0; r < 4; ++r) {
                int row = bm + wm * 64 + i * 16 + lg * 4 + r;
                C[(size_t)row * FM + col] = f2bf(acc[i][n][r]);
            }
        }
    }
}

// ---------------------------------------------------------------------------
// Fused GCN aggregation: CSR gather over bf16 h -> bf16 branch out + fused
// pre-rounding fp32 pooled sum.
// out[d][:] = relu( b + dinv[d]^2*h[d][:] + sum_j norm_j*h[src_j][:] )
// One wave per node; lane owns 4 bf16 (8B); unroll-4, 2 chains (r18 body).
// ---------------------------------------------------------------------------
__global__ __launch_bounds__(256) void gcn_aggregate_csr(const ushort* __restrict__ h,
                                                         const int* __restrict__ row_start,
                                                         const int* __restrict__ csr_src,
                                                         const float* __restrict__ csr_norm,
                                                         const float* __restrict__ dinv,
                                                         const float* __restrict__ bias,
                                                         ushort* __restrict__ out,
                                                         float* __restrict__ pooled,
                                                         int bidx) {
    int node = blockIdx.x * 4 + (threadIdx.x >> 6);
    int lane = threadIdx.x & 63;
    const ushort4* hp = (const ushort4*)h;

    float di = dinv[node];
    float sw = di * di;
    ushort4 q = hp[(size_t)node * 64 + lane];
    float4 accA = make_float4(bf2f(q.x) * sw, bf2f(q.y) * sw,
                              bf2f(q.z) * sw, bf2f(q.w) * sw);
    float4 accB = make_float4(0.f, 0.f, 0.f, 0.f);

    int beg = row_start[node];
    int end = row_start[node + 1];
    int j = beg;
    for (; j + 3 < end; j += 4) {
        int s0 = csr_src[j];
        int s1 = csr_src[j + 1];
        int s2 = csr_src[j + 2];
        int s3 = csr_src[j + 3];
        float w0 = csr_norm[j];
        float w1 = csr_norm[j + 1];
        float w2 = csr_norm[j + 2];
        float w3 = csr_norm[j + 3];
        ushort4 q0 = hp[(size_t)s0 * 64 + lane];
        ushort4 q1 = hp[(size_t)s1 * 64 + lane];
        ushort4 q2 = hp[(size_t)s2 * 64 + lane];
        ushort4 q3 = hp[(size_t)s3 * 64 + lane];
        accA.x += w0 * bf2f(q0.x) + w1 * bf2f(q1.x);
        accA.y += w0 * bf2f(q0.y) + w1 * bf2f(q1.y);
        accA.z += w0 * bf2f(q0.z) + w1 * bf2f(q1.z);
        accA.w += w0 * bf2f(q0.w) + w1 * bf2f(q1.w);
        accB.x += w2 * bf2f(q2.x) + w3 * bf2f(q3.x);
        accB.y += w2 * bf2f(q2.y) + w3 * bf2f(q3.y);
        accB.z += w2 * bf2f(q2.z) + w3 * bf2f(q3.z);
        accB.w += w2 * bf2f(q2.w) + w3 * bf2f(q3.w);
    }
    for (; j < end; ++j) {
        int s0 = csr_src[j];
        float w0 = csr_norm[j];
        ushort4 q0 = hp[(size_t)s0 * 64 + lane];
        accA.x += w0 * bf2f(q0.x);
        accA.y += w0 * bf2f(q0.y);
        accA.z += w0 * bf2f(q0.z);
        accA.w += w0 * bf2f(q0.w);
    }
    float4 bb = ((const float4*)bias)[lane];
    float4 r;
    r.x = fmaxf(accA.x + accB.x + bb.x, 0.0f);
    r.y = fmaxf(accA.y + accB.y + bb.y, 0.0f);
    r.z = fmaxf(accA.z + accB.z + bb.z, 0.0f);
    r.w = fmaxf(accA.w + accB.w + bb.w, 0.0f);
    ushort4 o;
    o.x = f2bf(r.x); o.y = f2bf(r.y); o.z = f2bf(r.z); o.w = f2bf(r.w);
    ((ushort4*)out)[(size_t)node * 64 + lane] = o;

    // fused pooled-sum (pre-rounding fp32)
    float psum = r.x + r.y + r.z + r.w;
    for (int o2 = 32; o2 > 0; o2 >>= 1) psum += __shfl_down(psum, o2);
    __shared__ float wsum[4];
    if (lane == 0) wsum[threadIdx.x >> 6] = psum;
    __syncthreads();
    if (threadIdx.x == 0)
        atomicAdd(&pooled[bidx], wsum[0] + wsum[1] + wsum[2] + wsum[3]);
}

// ---------------------------------------------------------------------------
// SE attention MLP
// ---------------------------------------------------------------------------
__global__ void se_kernel(const float* __restrict__ pooled_sum,
                          const float* __restrict__ fc1_w, const float* __restrict__ fc1_b,
                          const float* __restrict__ fc2_w, const float* __restrict__ fc2_b,
                          float* __restrict__ att) {
    __shared__ float p[6];
    __shared__ float hbuf[30];
    int t = threadIdx.x;
    if (t < 6) p[t] = pooled_sum[t] * (1.0f / ((float)N_NODES * (float)FM));
    __syncthreads();
    if (t < 30) {
        float a = fc1_b[t];
#pragma unroll
        for (int c = 0; c < 6; ++c) a += fc1_w[t * 6 + c] * p[c];
        hbuf[t] = fmaxf(a, 0.0f);
    }
    __syncthreads();
    if (t < 6) {
        float a = fc2_b[t];
#pragma unroll
        for (int j = 0; j < 30; ++j) a += fc2_w[t * 30 + j] * hbuf[j];
        att[t] = 1.0f / (1.0f + expf(-a));
    }
}

// out[n][f] = sum_c cnn_w[c] * relu(att[c] * br_c[n][f]) + cnn_b  (br bf16)
__global__ void combine_kernel(const ushort* __restrict__ br,
                               const float* __restrict__ att,
                               const float* __restrict__ cnn_w,
                               const float* __restrict__ cnn_b,
                               float* __restrict__ out, int total4) {
    int i = blockIdx.x * blockDim.x + threadIdx.x;
    if (i >= total4) return;
    float a[6], w[6];
#pragma unroll
    for (int c = 0; c < 6; ++c) { a[c] = att[c]; w[c] = cnn_w[c]; }
    float cb = cnn_b[0];
    float4 acc = make_float4(cb, cb, cb, cb);
#pragma unroll
    for (int c = 0; c < 6; ++c) {
        ushort4 q = ((const ushort4*)(br + (size_t)c * NF))[i];
        acc.x += w[c] * fmaxf(a[c] * bf2f(q.x), 0.0f);
        acc.y += w[c] * fmaxf(a[c] * bf2f(q.y), 0.0f);
        acc.z += w[c] * fmaxf(a[c] * bf2f(q.z), 0.0f);
        acc.w += w[c] * fmaxf(a[c] * bf2f(q.w), 0.0f);
    }
    ((float4*)out)[i] = acc;
}

// ---------------------------------------------------------------------------
// Host orchestration
// ---------------------------------------------------------------------------

static void run_conv(const ushort* inA, const ushort* wtp, const float* b,
                     const int* row_start, const int* csr_src, const float* csr_norm,
                     const float* dinv, ushort* h_bf16, ushort* out,
                     float* pooled, int bidx, hipStream_t stream) {
    dim3 ggrid(N_NODES / 128, FM / 64);
    gemm_mfma<<<ggrid, 256, 0, stream>>>(inA, wtp, h_bf16);
    gcn_aggregate_csr<<<N_NODES / 4, 256, 0, stream>>>(h_bf16, row_start, csr_src,
                                                       csr_norm, dinv, b, out,
                                                       pooled, bidx);
}

extern "C" void kernel_launch(void* const* d_in, const int* in_sizes, int n_in,
                              void* d_out, int out_size, void* d_ws, size_t ws_size,
                              hipStream_t stream) {
    const float* x      = (const float*)d_in[0];
    const int*   ed_f   = (const int*)d_in[1];
    const float* ew_f   = (const float*)d_in[2];
    const int*   ed_s   = (const int*)d_in[3];
    const float* ew_s   = (const float*)d_in[4];
    const int*   ed_g   = (const int*)d_in[5];
    const float* ew_g   = (const float*)d_in[6];
    const float* Wf1 = (const float*)d_in[7];  const float* bf1 = (const float*)d_in[8];
    const float* Wf2 = (const float*)d_in[9];  const float* bf2 = (const float*)d_in[10];
    const float* Ws1 = (const float*)d_in[11]; const float* bs1 = (const float*)d_in[12];
    const float* Ws2 = (const float*)d_in[13]; const float* bs2 = (const float*)d_in[14];
    const float* Wg1 = (const float*)d_in[15]; const float* bg1 = (const float*)d_in[16];
    const float* Wg2 = (const float*)d_in[17]; const float* bg2 = (const float*)d_in[18];
    const float* fc1_w = (const float*)d_in[19]; const float* fc1_b = (const float*)d_in[20];
    const float* fc2_w = (const float*)d_in[21]; const float* fc2_b = (const float*)d_in[22];
    const float* cnn_w = (const float*)d_in[23]; const float* cnn_b = (const float*)d_in[24];

    const int E = in_sizes[1] / 2;   // 524288

    // Workspace layout:
    ushort* br_u = (ushort*)d_ws;                      // 6*NF bf16 branch outputs
    ushort* xb   = br_u + (size_t)6 * NF;              // NF bf16 (x converted)
    ushort* wt   = xb + NF;                            // 6*FM*FM bf16 (WT packed)
    float*  dinv3  = (float*)(wt + 6 * FM * FM);       // 3*N_NODES
    float*  pooled = dinv3 + 3 * N_NODES;              // 8
    float*  att    = pooled + 8;                       // 8
    int*    cnt3       = (int*)(att + 8);              // 3*NSCAN
    int*    cursor3    = cnt3 + 3 * NSCAN;             // 3*NSCAN
    int*    rowstart3  = cursor3 + 3 * NSCAN;          // 3*RS_STRIDE
    int*    nodestart3 = rowstart3 + 3 * RS_STRIDE;    // 3*NRS_STRIDE
    int*    tot3       = nodestart3 + 3 * NRS_STRIDE + 2;  // 3*N_NODES
    int*    psum       = tot3 + 3 * N_NODES;           // 3*NCHUNK
    int*    npsum      = psum + 3 * NCHUNK;            // 3*NCHUNK_N (+pad)
    int2*   csr3       = (int2*)(npsum + 3 * NCHUNK_N + 8);  // 3*E int2 (partitioned)
    int*    csr_src3   = (int*)(csr3 + (size_t)3 * E); // 3*E int (contiguous)
    float*  csr_norm3  = (float*)(csr_src3 + (size_t)3 * E);  // 3*E float

    float* dinv_set[3] = { dinv3, dinv3 + N_NODES, dinv3 + 2 * N_NODES };
    int*   nrs_set[3]  = { nodestart3, nodestart3 + NRS_STRIDE,
                           nodestart3 + 2 * NRS_STRIDE };
    int*   csrc_set[3] = { csr_src3, csr_src3 + E, csr_src3 + 2 * E };
    float* cnorm_set[3] = { csr_norm3, csr_norm3 + E, csr_norm3 + 2 * E };

    ushort* f1 = br_u + (size_t)0 * NF;
    ushort* f2 = br_u + (size_t)1 * NF;
    ushort* s1 = br_u + (size_t)2 * NF;
    ushort* s2 = br_u + (size_t)3 * NF;
    ushort* g1 = br_u + (size_t)4 * NF;
    ushort* g2 = br_u + (size_t)5 * NF;

    ushort* h = (ushort*)d_out;   // bf16 GEMM scratch; dead before combine

    // --- partitioned CSR build with parallel hierarchical scans ---
    init_kernel<<<(3 * NSCAN + 6 + 255) / 256, 256, 0, stream>>>(cnt3, pooled);
    {
        dim3 g((E + 255) / 256, 3);
        cnt_edges_all<<<g, 256, 0, stream>>>(ed_f + E, ed_s + E, ed_g + E, cnt3, E);
    }
    tot_kernel<<<(3 * N_NODES + 255) / 256, 256, 0, stream>>>(cnt3, tot3);
    {
        dim3 g1d(NCHUNK, 3);
        chunk_sum<<<g1d, 1024, 0, stream>>>(cnt3, (long)NSCAN, psum, NCHUNK);
        dim3 g2d(NCHUNK_N, 3);
        chunk_sum<<<g2d, 1024, 0, stream>>>(tot3, (long)N_NODES, npsum, NCHUNK_N);
    }
    scan_chunks<<<1, 128, 0, stream>>>(psum, npsum);
    {
        dim3 g1d(NCHUNK, 3);
        scan_write_rs<<<g1d, 1024, 0, stream>>>(cnt3, psum, rowstart3, cursor3);
        dim3 g2d(NCHUNK_N, 3);
        scan_write_nrs<<<g2d, 1024, 0, stream>>>(tot3, npsum, nodestart3);
    }
    {
        dim3 g((E + 255) / 256, 3);
        scatter_all<<<g, 256, 0, stream>>>(ed_f, ed_s, ed_g, ew_f, ew_s, ew_g,
                                           cursor3, csr3, E);
    }
    {
        dim3 g(N_NODES / 4, 3);
        deg_dinv_all<<<g, 256, 0, stream>>>(csr3, rowstart3, dinv3, E);
    }
    {
        dim3 g(N_NODES / 4, 3);
        compact_norm_all<<<g, 256, 0, stream>>>(csr3, rowstart3, nodestart3, dinv3,
                                                csr_src3, csr_norm3, E);
    }
    // --- weight pre-pack + x conversion ---
    {
        dim3 wg(16, 16, 6);
        wpack_kernel<<<wg, 256, 0, stream>>>(Wf1, Wf2, Ws1, Ws2, Wg1, Wg2, wt);
    }
    x2bf_kernel<<<(NF / 8 + 255) / 256, 256, 0, stream>>>(x, xb);

    const ushort* wt_set[6] = { wt, wt + 65536, wt + 2 * 65536,
                                wt + 3 * 65536, wt + 4 * 65536, wt + 5 * 65536 };

    // --- six GCN convs (branch idx = XM stack order f1,f2,s1,s2,g1,g2) ---
    run_conv(xb, wt_set[0], bf1, nrs_set[0], csrc_set[0], cnorm_set[0], dinv_set[0], h, f1, pooled, 0, stream);
    run_conv(f1, wt_set[1], bf2, nrs_set[0], csrc_set[0], cnorm_set[0], dinv_set[0], h, f2, pooled, 1, stream);
    run_conv(xb, wt_set[2], bs1, nrs_set[1], csrc_set[1], cnorm_set[1], dinv_set[1], h, s1, pooled, 2, stream);
    run_conv(s1, wt_set[3], bs2, nrs_set[1], csrc_set[1], cnorm_set[1], dinv_set[1], h, s2, pooled, 3, stream);
    run_conv(xb, wt_set[4], bg1, nrs_set[2], csrc_set[2], cnorm_set[2], dinv_set[2], h, g1, pooled, 4, stream);
    run_conv(g1, wt_set[5], bg2, nrs_set[2], csrc_set[2], cnorm_set[2], dinv_set[2], h, g2, pooled, 5, stream);

    // --- SE attention ---
    se_kernel<<<1, 64, 0, stream>>>(pooled, fc1_w, fc1_b, fc2_w, fc2_b, att);

    // --- final 1x1 conv combine ---
    combine_kernel<<<NF4 / 256, 256, 0, stream>>>(br_u, att, cnn_w, cnn_b,
                                                  (float*)d_out, NF4);
}

// Round 20
// 549.573 us; speedup vs baseline: 1.3272x; 1.3272x over previous
//
#include <hip/hip_runtime.h>
#include <hip/hip_bf16.h>

// Problem constants (from reference setup_inputs)
#define N_NODES 16384
#define FM      256
#define NF      (N_NODES * FM)          // 4,194,304 elements per branch tensor
#define NF4     (NF / 4)
#define NPART   8                       // CSR build partitions (~1 per XCD)
#define NSCAN   (NPART * N_NODES)       // 131072 counters per edge set
#define RS_STRIDE 131076                // NSCAN + sentinel + pad
#define NRS_STRIDE (N_NODES + 2)        // node-level row_start stride
#define NCHUNK 128                      // 1024-element chunks in NSCAN
#define NCHUNK_N 16                     // 1024-element chunks in N_NODES

typedef __attribute__((ext_vector_type(8))) short short8;
typedef __attribute__((ext_vector_type(8))) ushort ushort8;
typedef __attribute__((ext_vector_type(4))) float f32x4;

__device__ inline ushort f2bf(float f) {            // fp32 -> bf16 (RNE)
    uint u = __float_as_uint(f);
    return (ushort)((u + 0x7FFFu + ((u >> 16) & 1u)) >> 16);
}
__device__ inline uint pack2bf(float a, float b) {
    return (uint)f2bf(a) | ((uint)f2bf(b) << 16);
}
__device__ inline float bf2f(ushort u) { return __uint_as_float(((uint)u) << 16); }

// ---------------------------------------------------------------------------
// Init: partitioned edge-count histograms = 0, pooled = 0
// ---------------------------------------------------------------------------
__global__ void init_kernel(int* __restrict__ cnt3, float* __restrict__ pooled) {
    int i = blockIdx.x * blockDim.x + threadIdx.x;
    int n = 3 * NSCAN;
    if (i < n) cnt3[i] = 0;
    else if (i < n + 6) pooled[i - n] = 0.0f;
}

// Count histogram keyed by (set, part=blockIdx.x&7, dst): L2-local atomics.
__global__ void cnt_edges_all(const int* __restrict__ d0, const int* __restrict__ d1,
                              const int* __restrict__ d2,
                              int* __restrict__ cnt3, int E) {
    int t = blockIdx.y;
    const int* dst = (t == 0) ? d0 : (t == 1) ? d1 : d2;
    int part = blockIdx.x & (NPART - 1);
    int* cnt = cnt3 + t * NSCAN + part * N_NODES;
    int e = blockIdx.x * blockDim.x + threadIdx.x;
    if (e < E) atomicAdd(&cnt[__builtin_nontemporal_load(&dst[e])], 1);
}

// ---------------------------------------------------------------------------
// Hierarchical scans (parallel)
// ---------------------------------------------------------------------------

// tot[set][node] = sum_p cnt[set][p][node]
__global__ void tot_kernel(const int* __restrict__ cnt3, int* __restrict__ tot3) {
    int i = blockIdx.x * blockDim.x + threadIdx.x;     // over 3*N_NODES
    if (i >= 3 * N_NODES) return;
    int set = i / N_NODES;
    int node = i - set * N_NODES;
    const int* cnt = cnt3 + set * NSCAN;
    int s = 0;
#pragma unroll
    for (int p = 0; p < NPART; ++p) s += cnt[p * N_NODES + node];
    tot3[i] = s;
}

// Chunk sums: psum[set][chunk] = sum of src[set][chunk*1024 .. +1024)
__global__ __launch_bounds__(1024) void chunk_sum(const int* __restrict__ src,
                                                  long set_stride,
                                                  int* __restrict__ psum,
                                                  int nchunk) {
    int set = blockIdx.y;
    const int* p = src + (size_t)set * set_stride + (size_t)blockIdx.x * 1024;
    __shared__ int lds[1024];
    int t = threadIdx.x;
    lds[t] = p[t];
    __syncthreads();
    for (int off = 512; off > 0; off >>= 1) {
        if (t < off) lds[t] += lds[t + off];
        __syncthreads();
    }
    if (t == 0) psum[set * nchunk + blockIdx.x] = lds[0];
}

// Scan the chunk sums (3x128 and 3x16) -> exclusive chunk bases. One block.
__global__ __launch_bounds__(128) void scan_chunks(int* __restrict__ psum,
                                                   int* __restrict__ npsum) {
    __shared__ int lds[128];
    int t = threadIdx.x;
    for (int set = 0; set < 3; ++set) {
        int v = psum[set * NCHUNK + t];
        lds[t] = v;
        __syncthreads();
        for (int off = 1; off < 128; off <<= 1) {
            int u = (t >= off) ? lds[t - off] : 0;
            __syncthreads();
            lds[t] += u;
            __syncthreads();
        }
        psum[set * NCHUNK + t] = lds[t] - v;   // exclusive
        __syncthreads();
    }
    for (int set = 0; set < 3; ++set) {
        int v = (t < NCHUNK_N) ? npsum[set * NCHUNK_N + t] : 0;
        lds[t] = v;
        __syncthreads();
        for (int off = 1; off < NCHUNK_N; off <<= 1) {
            int u = (t >= off && t < NCHUNK_N) ? lds[t - off] : 0;
            __syncthreads();
            if (t < NCHUNK_N) lds[t] += u;
            __syncthreads();
        }
        if (t < NCHUNK_N) npsum[set * NCHUNK_N + t] = lds[t] - v;
        __syncthreads();
    }
}

// Final: local 1024-scan + chunk base -> row_start & cursor (partition-major).
__global__ __launch_bounds__(1024) void scan_write_rs(const int* __restrict__ cnt3,
                                                      const int* __restrict__ psum,
                                                      int* __restrict__ rowstart3,
                                                      int* __restrict__ cursor3) {
    int set = blockIdx.y;
    int base = psum[set * NCHUNK + blockIdx.x];
    const int* cnt = cnt3 + set * NSCAN + (size_t)blockIdx.x * 1024;
    int* rs = rowstart3 + set * RS_STRIDE + (size_t)blockIdx.x * 1024;
    int* cur = cursor3 + set * NSCAN + (size_t)blockIdx.x * 1024;
    __shared__ int lds[1024];
    int t = threadIdx.x;
    int v = cnt[t];
    lds[t] = v;
    __syncthreads();
    for (int off = 1; off < 1024; off <<= 1) {
        int u = (t >= off) ? lds[t - off] : 0;
        __syncthreads();
        lds[t] += u;
        __syncthreads();
    }
    int pre = base + lds[t] - v;    // exclusive
    rs[t] = pre;
    cur[t] = pre;
    if (blockIdx.x == NCHUNK - 1 && t == 1023)
        rowstart3[set * RS_STRIDE + NSCAN] = base + lds[t];
}

// Final: local 1024-scan + chunk base -> nodestart (node-major totals).
__global__ __launch_bounds__(1024) void scan_write_nrs(const int* __restrict__ tot3,
                                                       const int* __restrict__ npsum,
                                                       int* __restrict__ nodestart3) {
    int set = blockIdx.y;
    int base = npsum[set * NCHUNK_N + blockIdx.x];
    const int* tot = tot3 + (size_t)set * N_NODES + (size_t)blockIdx.x * 1024;
    int* nrs = nodestart3 + set * NRS_STRIDE + (size_t)blockIdx.x * 1024;
    __shared__ int lds[1024];
    int t = threadIdx.x;
    int v = tot[t];
    lds[t] = v;
    __syncthreads();
    for (int off = 1; off < 1024; off <<= 1) {
        int u = (t >= off) ? lds[t - off] : 0;
        __syncthreads();
        lds[t] += u;
        __syncthreads();
    }
    nrs[t] = base + lds[t] - v;     // exclusive
    if (blockIdx.x == NCHUNK_N - 1 && t == 1023)
        nodestart3[set * NRS_STRIDE + N_NODES] = base + lds[t];
}

// Scatter edges into partitioned CSR slots as packed {src, raw weight bits}.
__global__ void scatter_all(const int* __restrict__ s0, const int* __restrict__ s1,
                            const int* __restrict__ s2,
                            const float* __restrict__ e0, const float* __restrict__ e1,
                            const float* __restrict__ e2,
                            int* __restrict__ cursor3, int2* __restrict__ csr3, int E) {
    int t = blockIdx.y;
    const int* ed = (t == 0) ? s0 : (t == 1) ? s1 : s2;   // [2][E]: src row, dst row
    const float* ew = (t == 0) ? e0 : (t == 1) ? e1 : e2;
    int part = blockIdx.x & (NPART - 1);
    int* cursor = cursor3 + t * NSCAN + part * N_NODES;
    int2* csr = csr3 + (size_t)t * E;
    int e = blockIdx.x * blockDim.x + threadIdx.x;
    if (e >= E) return;
    int s = __builtin_nontemporal_load(&ed[e]);
    int d = __builtin_nontemporal_load(&ed[E + e]);
    float w = __builtin_nontemporal_load(&ew[e]);
    int pos = atomicAdd(&cursor[d], 1);
    csr[pos] = make_int2(s, __float_as_int(w));
}

// deg[d] = 1 + sum of row weights over the 8 partition segments; dinv=rsqrt.
__global__ __launch_bounds__(256) void deg_dinv_all(const int2* __restrict__ csr3,
                                                    const int* __restrict__ rowstart3,
                                                    float* __restrict__ dinv3, int E) {
    int t = blockIdx.y;
    const int2* csr = csr3 + (size_t)t * E;
    const int* rs = rowstart3 + t * RS_STRIDE;
    int node = blockIdx.x * 4 + (threadIdx.x >> 6);
    int lane = threadIdx.x & 63;
    int p = lane >> 3;
    int l8 = lane & 7;
    int beg = rs[p * N_NODES + node], end = rs[p * N_NODES + node + 1];
    float s = 0.0f;
    for (int j = beg + l8; j < end; j += 8)
        s += __int_as_float(csr[j].y);
    for (int o = 32; o > 0; o >>= 1) s += __shfl_down(s, o);
    if (lane == 0) dinv3[t * N_NODES + node] = rsqrtf(1.0f + s);
}

// Compact partitioned CSR -> contiguous csr_src[] + csr_norm[] with the FULL
// norm = w * dinv[src] * dinv[dst].
__global__ __launch_bounds__(256) void compact_norm_all(const int2* __restrict__ csr3,
                                                        const int* __restrict__ rowstart3,
                                                        const int* __restrict__ nodestart3,
                                                        const float* __restrict__ dinv3,
                                                        int* __restrict__ csrsrc3,
                                                        float* __restrict__ csrnorm3,
                                                        int E) {
    int t = blockIdx.y;
    const int2* src = csr3 + (size_t)t * E;
    const int* prs = rowstart3 + t * RS_STRIDE;
    const int* nrs = nodestart3 + t * NRS_STRIDE;
    const float* dinv = dinv3 + t * N_NODES;
    int* dsrc = csrsrc3 + (size_t)t * E;
    float* dnorm = csrnorm3 + (size_t)t * E;
    int node = blockIdx.x * 4 + (threadIdx.x >> 6);
    int lane = threadIdx.x & 63;
    float din = dinv[node];
    int w = nrs[node];
#pragma unroll
    for (int p = 0; p < NPART; ++p) {
        int beg = prs[p * N_NODES + node];
        int end = prs[p * N_NODES + node + 1];
        for (int j = beg + lane; j < end; j += 64) {
            int2 c = src[j];
            dsrc[w + (j - beg)] = c.x;
            dnorm[w + (j - beg)] = __int_as_float(c.y) * dinv[c.x] * din;
        }
        w += end - beg;
    }
}

// ---------------------------------------------------------------------------
// Weight pre-pack: WT[n][k] = bf16(W[k][n]) for all 6 weights (grid.z = widx).
// ---------------------------------------------------------------------------
__global__ __launch_bounds__(256) void wpack_kernel(const float* __restrict__ w0,
                                                    const float* __restrict__ w1,
                                                    const float* __restrict__ w2,
                                                    const float* __restrict__ w3,
                                                    const float* __restrict__ w4,
                                                    const float* __restrict__ w5,
                                                    ushort* __restrict__ wt) {
    const float* W;
    switch (blockIdx.z) {
        case 0: W = w0; break; case 1: W = w1; break; case 2: W = w2; break;
        case 3: W = w3; break; case 4: W = w4; break; default: W = w5; break;
    }
    __shared__ float tl[16][17];
    int tx = threadIdx.x & 15, ty = threadIdx.x >> 4;
    int k0 = blockIdx.x * 16, n0 = blockIdx.y * 16;
    tl[ty][tx] = W[(size_t)(k0 + ty) * FM + n0 + tx];
    __syncthreads();
    wt[(size_t)blockIdx.z * FM * FM + (size_t)(n0 + ty) * FM + k0 + tx] = f2bf(tl[tx][ty]);
}

// x (fp32) -> bf16 once; reused as GEMM A input by the 3 first-layer convs.
__global__ void x2bf_kernel(const float* __restrict__ x, ushort* __restrict__ xb) {
    int i = blockIdx.x * blockDim.x + threadIdx.x;   // over NF/8
    if (i >= NF / 8) return;
    const float4* xp = (const float4*)x;
    float4 a = xp[2 * i], b = xp[2 * i + 1];
    uint4 pk;
    pk.x = pack2bf(a.x, a.y);
    pk.y = pack2bf(a.z, a.w);
    pk.z = pack2bf(b.x, b.y);
    pk.w = pack2bf(b.z, b.w);
    ((uint4*)xb)[i] = pk;
}

// ---------------------------------------------------------------------------
// bf16 MFMA GEMM: C_bf16[M,256] = A_bf16[M,256] @ W (WT[n][k] bf16).
// BM=128, BN=64, BK=64; 4 waves (2x2); A staged to XOR-swizzled LDS (copy).
// ---------------------------------------------------------------------------
__global__ __launch_bounds__(256) void gemm_mfma(const ushort* __restrict__ A,
                                                 const ushort* __restrict__ WT,
                                                 ushort* __restrict__ C) {
    __shared__ ushort A_lds[128 * 64];

    const int tid = threadIdx.x;
    const int lane = tid & 63;
    const int wid = tid >> 6;
    const int wm = wid >> 1, wn = wid & 1;
    const int bm = blockIdx.x * 128;
    const int bn = blockIdx.y * 64;
    const int l15 = lane & 15;
    const int lg = lane >> 4;

    f32x4 acc[4][2];
#pragma unroll
    for (int i = 0; i < 4; ++i)
#pragma unroll
        for (int n = 0; n < 2; ++n) acc[i][n] = (f32x4){0.f, 0.f, 0.f, 0.f};

    const int srow = tid >> 1;
    const int shk = tid & 1;
    const ushort* arow_p = &A[(size_t)(bm + srow) * FM + shk * 32];

    for (int k0 = 0; k0 < 256; k0 += 64) {
        {
            const ushort* ap = arow_p + k0;
#pragma unroll
            for (int g = 0; g < 4; ++g) {
                ushort8 v = *(const ushort8*)(ap + g * 8);
                int kk = shk * 32 + g * 8;
                int idx = srow * 64 + (kk ^ ((srow & 7) << 3));
                *(ushort8*)&A_lds[idx] = v;
            }
        }
        __syncthreads();
#pragma unroll
        for (int s = 0; s < 2; ++s) {
            short8 bfrag[2];
#pragma unroll
            for (int n = 0; n < 2; ++n) {
                int col = bn + wn * 32 + n * 16 + l15;
                bfrag[n] = *(const short8*)&WT[(size_t)col * FM + k0 + s * 32 + lg * 8];
            }
#pragma unroll
            for (int i = 0; i < 4; ++i) {
                int row = wm * 64 + i * 16 + l15;
                int kk = s * 32 + lg * 8;
                short8 afrag = *(const short8*)&A_lds[row * 64 + (kk ^ ((row & 7) << 3))];
#pragma unroll
                for (int n = 0; n < 2; ++n)
                    acc[i][n] = __builtin_amdgcn_mfma_f32_16x16x32_bf16(
                        afrag, bfrag[n], acc[i][n], 0, 0, 0);
            }
        }
        __syncthreads();
    }
#pragma unroll
    for (int i = 0; i < 4; ++i) {
#pragma unroll
        for (int n = 0; n < 2; ++n) {
            int col = bn + wn * 32 + n * 16 + l15;
#pragma unroll
            for (int r = 0; r < 4; ++r) {
                int row = bm + wm * 64 + i * 16 + lg * 4 + r;
                C[(size_t)row * FM + col] = f2bf(acc[i][n][r]);
            }
        }
    }
}

// ---------------------------------------------------------------------------
// Fused GCN aggregation: CSR gather over bf16 h -> bf16 branch out.
// NO pooled-sum fusion (r19 lesson: the end-of-block barrier + same-address
// atomic couples waves of varying row length and cost ~20us/dispatch).
// out[d][:] = relu( b + dinv[d]^2*h[d][:] + sum_j norm_j*h[src_j][:] )
// One wave per node; lane owns 4 bf16 (8B); unroll-4, 2 chains.
// ---------------------------------------------------------------------------
__global__ __launch_bounds__(256) void gcn_aggregate_csr(const ushort* __restrict__ h,
                                                         const int* __restrict__ row_start,
                                                         const int* __restrict__ csr_src,
                                                         const float* __restrict__ csr_norm,
                                                         const float* __restrict__ dinv,
                                                         const float* __restrict__ bias,
                                                         ushort* __restrict__ out) {
    int node = blockIdx.x * 4 + (threadIdx.x >> 6);
    int lane = threadIdx.x & 63;
    const ushort4* hp = (const ushort4*)h;

    float di = dinv[node];
    float sw = di * di;
    ushort4 q = hp[(size_t)node * 64 + lane];
    float4 accA = make_float4(bf2f(q.x) * sw, bf2f(q.y) * sw,
                              bf2f(q.z) * sw, bf2f(q.w) * sw);
    float4 accB = make_float4(0.f, 0.f, 0.f, 0.f);

    int beg = row_start[node];
    int end = row_start[node + 1];
    int j = beg;
    for (; j + 3 < end; j += 4) {
        int s0 = csr_src[j];
        int s1 = csr_src[j + 1];
        int s2 = csr_src[j + 2];
        int s3 = csr_src[j + 3];
        float w0 = csr_norm[j];
        float w1 = csr_norm[j + 1];
        float w2 = csr_norm[j + 2];
        float w3 = csr_norm[j + 3];
        ushort4 q0 = hp[(size_t)s0 * 64 + lane];
        ushort4 q1 = hp[(size_t)s1 * 64 + lane];
        ushort4 q2 = hp[(size_t)s2 * 64 + lane];
        ushort4 q3 = hp[(size_t)s3 * 64 + lane];
        accA.x += w0 * bf2f(q0.x) + w1 * bf2f(q1.x);
        accA.y += w0 * bf2f(q0.y) + w1 * bf2f(q1.y);
        accA.z += w0 * bf2f(q0.z) + w1 * bf2f(q1.z);
        accA.w += w0 * bf2f(q0.w) + w1 * bf2f(q1.w);
        accB.x += w2 * bf2f(q2.x) + w3 * bf2f(q3.x);
        accB.y += w2 * bf2f(q2.y) + w3 * bf2f(q3.y);
        accB.z += w2 * bf2f(q2.z) + w3 * bf2f(q3.z);
        accB.w += w2 * bf2f(q2.w) + w3 * bf2f(q3.w);
    }
    for (; j < end; ++j) {
        int s0 = csr_src[j];
        float w0 = csr_norm[j];
        ushort4 q0 = hp[(size_t)s0 * 64 + lane];
        accA.x += w0 * bf2f(q0.x);
        accA.y += w0 * bf2f(q0.y);
        accA.z += w0 * bf2f(q0.z);
        accA.w += w0 * bf2f(q0.w);
    }
    float4 bb = ((const float4*)bias)[lane];
    float4 r;
    r.x = fmaxf(accA.x + accB.x + bb.x, 0.0f);
    r.y = fmaxf(accA.y + accB.y + bb.y, 0.0f);
    r.z = fmaxf(accA.z + accB.z + bb.z, 0.0f);
    r.w = fmaxf(accA.w + accB.w + bb.w, 0.0f);
    ushort4 o;
    o.x = f2bf(r.x); o.y = f2bf(r.y); o.z = f2bf(r.z); o.w = f2bf(r.w);
    ((ushort4*)out)[(size_t)node * 64 + lane] = o;
}

// ---------------------------------------------------------------------------
// SE attention: separate branch reduction over bf16 branch tensors.
// grid (256, 6): block handles 16384 elements of branch c.
// ---------------------------------------------------------------------------
__global__ __launch_bounds__(256) void reduce_branch_kernel(const ushort* __restrict__ br,
                                                            float* __restrict__ pooled) {
    int c = blockIdx.y;
    const ushort8* p = (const ushort8*)(br + (size_t)c * NF + (size_t)blockIdx.x * 16384);
    float s = 0.0f;
#pragma unroll
    for (int i = 0; i < 8; ++i) {
        ushort8 v = p[threadIdx.x + i * 256];
#pragma unroll
        for (int k = 0; k < 8; ++k) s += bf2f(v[k]);
    }
    for (int o = 32; o > 0; o >>= 1) s += __shfl_down(s, o);
    __shared__ float wsum[4];
    if ((threadIdx.x & 63) == 0) wsum[threadIdx.x >> 6] = s;
    __syncthreads();
    if (threadIdx.x == 0)
        atomicAdd(&pooled[c], wsum[0] + wsum[1] + wsum[2] + wsum[3]);
}

__global__ void se_kernel(const float* __restrict__ pooled_sum,
                          const float* __restrict__ fc1_w, const float* __restrict__ fc1_b,
                          const float* __restrict__ fc2_w, const float* __restrict__ fc2_b,
                          float* __restrict__ att) {
    __shared__ float p[6];
    __shared__ float hbuf[30];
    int t = threadIdx.x;
    if (t < 6) p[t] = pooled_sum[t] * (1.0f / ((float)N_NODES * (float)FM));
    __syncthreads();
    if (t < 30) {
        float a = fc1_b[t];
#pragma unroll
        for (int c = 0; c < 6; ++c) a += fc1_w[t * 6 + c] * p[c];
        hbuf[t] = fmaxf(a, 0.0f);
    }
    __syncthreads();
    if (t < 6) {
        float a = fc2_b[t];
#pragma unroll
        for (int j = 0; j < 30; ++j) a += fc2_w[t * 30 + j] * hbuf[j];
        att[t] = 1.0f / (1.0f + expf(-a));
    }
}

// out[n][f] = sum_c cnn_w[c] * relu(att[c] * br_c[n][f]) + cnn_b  (br bf16)
__global__ void combine_kernel(const ushort* __restrict__ br,
                               const float* __restrict__ att,
                               const float* __restrict__ cnn_w,
                               const float* __restrict__ cnn_b,
                               float* __restrict__ out, int total4) {
    int i = blockIdx.x * blockDim.x + threadIdx.x;
    if (i >= total4) return;
    float a[6], w[6];
#pragma unroll
    for (int c = 0; c < 6; ++c) { a[c] = att[c]; w[c] = cnn_w[c]; }
    float cb = cnn_b[0];
    float4 acc = make_float4(cb, cb, cb, cb);
#pragma unroll
    for (int c = 0; c < 6; ++c) {
        ushort4 q = ((const ushort4*)(br + (size_t)c * NF))[i];
        acc.x += w[c] * fmaxf(a[c] * bf2f(q.x), 0.0f);
        acc.y += w[c] * fmaxf(a[c] * bf2f(q.y), 0.0f);
        acc.z += w[c] * fmaxf(a[c] * bf2f(q.z), 0.0f);
        acc.w += w[c] * fmaxf(a[c] * bf2f(q.w), 0.0f);
    }
    ((float4*)out)[i] = acc;
}

// ---------------------------------------------------------------------------
// Host orchestration
// ---------------------------------------------------------------------------

static void run_conv(const ushort* inA, const ushort* wtp, const float* b,
                     const int* row_start, const int* csr_src, const float* csr_norm,
                     const float* dinv, ushort* h_bf16, ushort* out,
                     hipStream_t stream) {
    dim3 ggrid(N_NODES / 128, FM / 64);
    gemm_mfma<<<ggrid, 256, 0, stream>>>(inA, wtp, h_bf16);
    gcn_aggregate_csr<<<N_NODES / 4, 256, 0, stream>>>(h_bf16, row_start, csr_src,
                                                       csr_norm, dinv, b, out);
}

extern "C" void kernel_launch(void* const* d_in, const int* in_sizes, int n_in,
                              void* d_out, int out_size, void* d_ws, size_t ws_size,
                              hipStream_t stream) {
    const float* x      = (const float*)d_in[0];
    const int*   ed_f   = (const int*)d_in[1];
    const float* ew_f   = (const float*)d_in[2];
    const int*   ed_s   = (const int*)d_in[3];
    const float* ew_s   = (const float*)d_in[4];
    const int*   ed_g   = (const int*)d_in[5];
    const float* ew_g   = (const float*)d_in[6];
    const float* Wf1 = (const float*)d_in[7];  const float* bf1 = (const float*)d_in[8];
    const float* Wf2 = (const float*)d_in[9];  const float* bf2 = (const float*)d_in[10];
    const float* Ws1 = (const float*)d_in[11]; const float* bs1 = (const float*)d_in[12];
    const float* Ws2 = (const float*)d_in[13]; const float* bs2 = (const float*)d_in[14];
    const float* Wg1 = (const float*)d_in[15]; const float* bg1 = (const float*)d_in[16];
    const float* Wg2 = (const float*)d_in[17]; const float* bg2 = (const float*)d_in[18];
    const float* fc1_w = (const float*)d_in[19]; const float* fc1_b = (const float*)d_in[20];
    const float* fc2_w = (const float*)d_in[21]; const float* fc2_b = (const float*)d_in[22];
    const float* cnn_w = (const float*)d_in[23]; const float* cnn_b = (const float*)d_in[24];

    const int E = in_sizes[1] / 2;   // 524288

    // Workspace layout:
    ushort* br_u = (ushort*)d_ws;                      // 6*NF bf16 branch outputs
    ushort* xb   = br_u + (size_t)6 * NF;              // NF bf16 (x converted)
    ushort* wt   = xb + NF;                            // 6*FM*FM bf16 (WT packed)
    float*  dinv3  = (float*)(wt + 6 * FM * FM);       // 3*N_NODES
    float*  pooled = dinv3 + 3 * N_NODES;              // 8
    float*  att    = pooled + 8;                       // 8
    int*    cnt3       = (int*)(att + 8);              // 3*NSCAN
    int*    cursor3    = cnt3 + 3 * NSCAN;             // 3*NSCAN
    int*    rowstart3  = cursor3 + 3 * NSCAN;          // 3*RS_STRIDE
    int*    nodestart3 = rowstart3 + 3 * RS_STRIDE;    // 3*NRS_STRIDE
    int*    tot3       = nodestart3 + 3 * NRS_STRIDE + 2;  // 3*N_NODES
    int*    psum       = tot3 + 3 * N_NODES;           // 3*NCHUNK
    int*    npsum      = psum + 3 * NCHUNK;            // 3*NCHUNK_N (+pad)
    int2*   csr3       = (int2*)(npsum + 3 * NCHUNK_N + 8);  // 3*E int2 (partitioned)
    int*    csr_src3   = (int*)(csr3 + (size_t)3 * E); // 3*E int (contiguous)
    float*  csr_norm3  = (float*)(csr_src3 + (size_t)3 * E);  // 3*E float

    float* dinv_set[3] = { dinv3, dinv3 + N_NODES, dinv3 + 2 * N_NODES };
    int*   nrs_set[3]  = { nodestart3, nodestart3 + NRS_STRIDE,
                           nodestart3 + 2 * NRS_STRIDE };
    int*   csrc_set[3] = { csr_src3, csr_src3 + E, csr_src3 + 2 * E };
    float* cnorm_set[3] = { csr_norm3, csr_norm3 + E, csr_norm3 + 2 * E };

    ushort* f1 = br_u + (size_t)0 * NF;
    ushort* f2 = br_u + (size_t)1 * NF;
    ushort* s1 = br_u + (size_t)2 * NF;
    ushort* s2 = br_u + (size_t)3 * NF;
    ushort* g1 = br_u + (size_t)4 * NF;
    ushort* g2 = br_u + (size_t)5 * NF;

    ushort* h = (ushort*)d_out;   // bf16 GEMM scratch; dead before combine

    // --- partitioned CSR build with parallel hierarchical scans ---
    init_kernel<<<(3 * NSCAN + 6 + 255) / 256, 256, 0, stream>>>(cnt3, pooled);
    {
        dim3 g((E + 255) / 256, 3);
        cnt_edges_all<<<g, 256, 0, stream>>>(ed_f + E, ed_s + E, ed_g + E, cnt3, E);
    }
    tot_kernel<<<(3 * N_NODES + 255) / 256, 256, 0, stream>>>(cnt3, tot3);
    {
        dim3 g1d(NCHUNK, 3);
        chunk_sum<<<g1d, 1024, 0, stream>>>(cnt3, (long)NSCAN, psum, NCHUNK);
        dim3 g2d(NCHUNK_N, 3);
        chunk_sum<<<g2d, 1024, 0, stream>>>(tot3, (long)N_NODES, npsum, NCHUNK_N);
    }
    scan_chunks<<<1, 128, 0, stream>>>(psum, npsum);
    {
        dim3 g1d(NCHUNK, 3);
        scan_write_rs<<<g1d, 1024, 0, stream>>>(cnt3, psum, rowstart3, cursor3);
        dim3 g2d(NCHUNK_N, 3);
        scan_write_nrs<<<g2d, 1024, 0, stream>>>(tot3, npsum, nodestart3);
    }
    {
        dim3 g((E + 255) / 256, 3);
        scatter_all<<<g, 256, 0, stream>>>(ed_f, ed_s, ed_g, ew_f, ew_s, ew_g,
                                           cursor3, csr3, E);
    }
    {
        dim3 g(N_NODES / 4, 3);
        deg_dinv_all<<<g, 256, 0, stream>>>(csr3, rowstart3, dinv3, E);
    }
    {
        dim3 g(N_NODES / 4, 3);
        compact_norm_all<<<g, 256, 0, stream>>>(csr3, rowstart3, nodestart3, dinv3,
                                                csr_src3, csr_norm3, E);
    }
    // --- weight pre-pack + x conversion ---
    {
        dim3 wg(16, 16, 6);
        wpack_kernel<<<wg, 256, 0, stream>>>(Wf1, Wf2, Ws1, Ws2, Wg1, Wg2, wt);
    }
    x2bf_kernel<<<(NF / 8 + 255) / 256, 256, 0, stream>>>(x, xb);

    const ushort* wt_set[6] = { wt, wt + 65536, wt + 2 * 65536,
                                wt + 3 * 65536, wt + 4 * 65536, wt + 5 * 65536 };

    // --- six GCN convs ---
    run_conv(xb, wt_set[0], bf1, nrs_set[0], csrc_set[0], cnorm_set[0], dinv_set[0], h, f1, stream);
    run_conv(f1, wt_set[1], bf2, nrs_set[0], csrc_set[0], cnorm_set[0], dinv_set[0], h, f2, stream);
    run_conv(xb, wt_set[2], bs1, nrs_set[1], csrc_set[1], cnorm_set[1], dinv_set[1], h, s1, stream);
    run_conv(s1, wt_set[3], bs2, nrs_set[1], csrc_set[1], cnorm_set[1], dinv_set[1], h, s2, stream);
    run_conv(xb, wt_set[4], bg1, nrs_set[2], csrc_set[2], cnorm_set[2], dinv_set[2], h, g1, stream);
    run_conv(g1, wt_set[5], bg2, nrs_set[2], csrc_set[2], cnorm_set[2], dinv_set[2], h, g2, stream);

    // --- SE attention ---
    {
        dim3 rgrid(256, 6);
        reduce_branch_kernel<<<rgrid, 256, 0, stream>>>(br_u, pooled);
    }
    se_kernel<<<1, 64, 0, stream>>>(pooled, fc1_w, fc1_b, fc2_w, fc2_b, att);

    // --- final 1x1 conv combine ---
    combine_kernel<<<NF4 / 256, 256, 0, stream>>>(br_u, att, cnn_w, cnn_b,
                                                  (float*)d_out, NF4);
}

// Round 21
// 507.015 us; speedup vs baseline: 1.4387x; 1.0839x over previous
//
#include <hip/hip_runtime.h>
#include <hip/hip_bf16.h>

// Problem constants (from reference setup_inputs)
#define N_NODES 16384
#define FM      256
#define NF      (N_NODES * FM)          // 4,194,304 elements per branch tensor
#define NF4     (NF / 4)
#define NPART   8                       // CSR build partitions (~1 per XCD)
#define NSCAN   (NPART * N_NODES)       // 131072 counters per edge set
#define RS_STRIDE 131076                // NSCAN + sentinel + pad
#define NRS_STRIDE (N_NODES + 2)        // node-level row_start stride
#define NCHUNK 128                      // 1024-element chunks in NSCAN
#define NCHUNK_N 16                     // 1024-element chunks in N_NODES

typedef __attribute__((ext_vector_type(8))) short short8;
typedef __attribute__((ext_vector_type(8))) ushort ushort8;
typedef __attribute__((ext_vector_type(4))) float f32x4;

__device__ inline ushort f2bf(float f) {            // fp32 -> bf16 (RNE)
    uint u = __float_as_uint(f);
    return (ushort)((u + 0x7FFFu + ((u >> 16) & 1u)) >> 16);
}
__device__ inline uint pack2bf(float a, float b) {
    return (uint)f2bf(a) | ((uint)f2bf(b) << 16);
}
__device__ inline float bf2f(ushort u) { return __uint_as_float(((uint)u) << 16); }

// ---------------------------------------------------------------------------
// Init: partitioned edge-count histograms = 0, pooled = 0
// ---------------------------------------------------------------------------
__global__ void init_kernel(int* __restrict__ cnt3, float* __restrict__ pooled) {
    int i = blockIdx.x * blockDim.x + threadIdx.x;
    int n = 3 * NSCAN;
    if (i < n) cnt3[i] = 0;
    else if (i < n + 6) pooled[i - n] = 0.0f;
}

// Count histogram keyed by (set, part=blockIdx.x&7, dst): L2-local atomics.
__global__ void cnt_edges_all(const int* __restrict__ d0, const int* __restrict__ d1,
                              const int* __restrict__ d2,
                              int* __restrict__ cnt3, int E) {
    int t = blockIdx.y;
    const int* dst = (t == 0) ? d0 : (t == 1) ? d1 : d2;
    int part = blockIdx.x & (NPART - 1);
    int* cnt = cnt3 + t * NSCAN + part * N_NODES;
    int e = blockIdx.x * blockDim.x + threadIdx.x;
    if (e < E) atomicAdd(&cnt[__builtin_nontemporal_load(&dst[e])], 1);
}

// ---------------------------------------------------------------------------
// Hierarchical scans (parallel)
// ---------------------------------------------------------------------------

// tot[set][node] = sum_p cnt[set][p][node]
__global__ void tot_kernel(const int* __restrict__ cnt3, int* __restrict__ tot3) {
    int i = blockIdx.x * blockDim.x + threadIdx.x;     // over 3*N_NODES
    if (i >= 3 * N_NODES) return;
    int set = i / N_NODES;
    int node = i - set * N_NODES;
    const int* cnt = cnt3 + set * NSCAN;
    int s = 0;
#pragma unroll
    for (int p = 0; p < NPART; ++p) s += cnt[p * N_NODES + node];
    tot3[i] = s;
}

// Chunk sums: psum[set][chunk] = sum of src[set][chunk*1024 .. +1024)
__global__ __launch_bounds__(1024) void chunk_sum(const int* __restrict__ src,
                                                  long set_stride,
                                                  int* __restrict__ psum,
                                                  int nchunk) {
    int set = blockIdx.y;
    const int* p = src + (size_t)set * set_stride + (size_t)blockIdx.x * 1024;
    __shared__ int lds[1024];
    int t = threadIdx.x;
    lds[t] = p[t];
    __syncthreads();
    for (int off = 512; off > 0; off >>= 1) {
        if (t < off) lds[t] += lds[t + off];
        __syncthreads();
    }
    if (t == 0) psum[set * nchunk + blockIdx.x] = lds[0];
}

// Scan the chunk sums (3x128 and 3x16) -> exclusive chunk bases. One block.
__global__ __launch_bounds__(128) void scan_chunks(int* __restrict__ psum,
                                                   int* __restrict__ npsum) {
    __shared__ int lds[128];
    int t = threadIdx.x;
    for (int set = 0; set < 3; ++set) {
        int v = psum[set * NCHUNK + t];
        lds[t] = v;
        __syncthreads();
        for (int off = 1; off < 128; off <<= 1) {
            int u = (t >= off) ? lds[t - off] : 0;
            __syncthreads();
            lds[t] += u;
            __syncthreads();
        }
        psum[set * NCHUNK + t] = lds[t] - v;   // exclusive
        __syncthreads();
    }
    for (int set = 0; set < 3; ++set) {
        int v = (t < NCHUNK_N) ? npsum[set * NCHUNK_N + t] : 0;
        lds[t] = v;
        __syncthreads();
        for (int off = 1; off < NCHUNK_N; off <<= 1) {
            int u = (t >= off && t < NCHUNK_N) ? lds[t - off] : 0;
            __syncthreads();
            if (t < NCHUNK_N) lds[t] += u;
            __syncthreads();
        }
        if (t < NCHUNK_N) npsum[set * NCHUNK_N + t] = lds[t] - v;
        __syncthreads();
    }
}

// Final: local 1024-scan + chunk base -> row_start & cursor (partition-major).
__global__ __launch_bounds__(1024) void scan_write_rs(const int* __restrict__ cnt3,
                                                      const int* __restrict__ psum,
                                                      int* __restrict__ rowstart3,
                                                      int* __restrict__ cursor3) {
    int set = blockIdx.y;
    int base = psum[set * NCHUNK + blockIdx.x];
    const int* cnt = cnt3 + set * NSCAN + (size_t)blockIdx.x * 1024;
    int* rs = rowstart3 + set * RS_STRIDE + (size_t)blockIdx.x * 1024;
    int* cur = cursor3 + set * NSCAN + (size_t)blockIdx.x * 1024;
    __shared__ int lds[1024];
    int t = threadIdx.x;
    int v = cnt[t];
    lds[t] = v;
    __syncthreads();
    for (int off = 1; off < 1024; off <<= 1) {
        int u = (t >= off) ? lds[t - off] : 0;
        __syncthreads();
        lds[t] += u;
        __syncthreads();
    }
    int pre = base + lds[t] - v;    // exclusive
    rs[t] = pre;
    cur[t] = pre;
    if (blockIdx.x == NCHUNK - 1 && t == 1023)
        rowstart3[set * RS_STRIDE + NSCAN] = base + lds[t];
}

// Final: local 1024-scan + chunk base -> nodestart (node-major totals).
__global__ __launch_bounds__(1024) void scan_write_nrs(const int* __restrict__ tot3,
                                                       const int* __restrict__ npsum,
                                                       int* __restrict__ nodestart3) {
    int set = blockIdx.y;
    int base = npsum[set * NCHUNK_N + blockIdx.x];
    const int* tot = tot3 + (size_t)set * N_NODES + (size_t)blockIdx.x * 1024;
    int* nrs = nodestart3 + set * NRS_STRIDE + (size_t)blockIdx.x * 1024;
    __shared__ int lds[1024];
    int t = threadIdx.x;
    int v = tot[t];
    lds[t] = v;
    __syncthreads();
    for (int off = 1; off < 1024; off <<= 1) {
        int u = (t >= off) ? lds[t - off] : 0;
        __syncthreads();
        lds[t] += u;
        __syncthreads();
    }
    nrs[t] = base + lds[t] - v;     // exclusive
    if (blockIdx.x == NCHUNK_N - 1 && t == 1023)
        nodestart3[set * NRS_STRIDE + N_NODES] = base + lds[t];
}

// Scatter edges into partitioned CSR slots as packed {src, raw weight bits}.
__global__ void scatter_all(const int* __restrict__ s0, const int* __restrict__ s1,
                            const int* __restrict__ s2,
                            const float* __restrict__ e0, const float* __restrict__ e1,
                            const float* __restrict__ e2,
                            int* __restrict__ cursor3, int2* __restrict__ csr3, int E) {
    int t = blockIdx.y;
    const int* ed = (t == 0) ? s0 : (t == 1) ? s1 : s2;   // [2][E]: src row, dst row
    const float* ew = (t == 0) ? e0 : (t == 1) ? e1 : e2;
    int part = blockIdx.x & (NPART - 1);
    int* cursor = cursor3 + t * NSCAN + part * N_NODES;
    int2* csr = csr3 + (size_t)t * E;
    int e = blockIdx.x * blockDim.x + threadIdx.x;
    if (e >= E) return;
    int s = __builtin_nontemporal_load(&ed[e]);
    int d = __builtin_nontemporal_load(&ed[E + e]);
    float w = __builtin_nontemporal_load(&ew[e]);
    int pos = atomicAdd(&cursor[d], 1);
    csr[pos] = make_int2(s, __float_as_int(w));
}

// deg[d] = 1 + sum of row weights over the 8 partition segments; dinv=rsqrt.
__global__ __launch_bounds__(256) void deg_dinv_all(const int2* __restrict__ csr3,
                                                    const int* __restrict__ rowstart3,
                                                    float* __restrict__ dinv3, int E) {
    int t = blockIdx.y;
    const int2* csr = csr3 + (size_t)t * E;
    const int* rs = rowstart3 + t * RS_STRIDE;
    int node = blockIdx.x * 4 + (threadIdx.x >> 6);
    int lane = threadIdx.x & 63;
    int p = lane >> 3;
    int l8 = lane & 7;
    int beg = rs[p * N_NODES + node], end = rs[p * N_NODES + node + 1];
    float s = 0.0f;
    for (int j = beg + l8; j < end; j += 8)
        s += __int_as_float(csr[j].y);
    for (int o = 32; o > 0; o >>= 1) s += __shfl_down(s, o);
    if (lane == 0) dinv3[t * N_NODES + node] = rsqrtf(1.0f + s);
}

// Compact partitioned CSR -> contiguous csr_src[] + csr_norm[] with the FULL
// norm = w * dinv[src] * dinv[dst].
__global__ __launch_bounds__(256) void compact_norm_all(const int2* __restrict__ csr3,
                                                        const int* __restrict__ rowstart3,
                                                        const int* __restrict__ nodestart3,
                                                        const float* __restrict__ dinv3,
                                                        int* __restrict__ csrsrc3,
                                                        float* __restrict__ csrnorm3,
                                                        int E) {
    int t = blockIdx.y;
    const int2* src = csr3 + (size_t)t * E;
    const int* prs = rowstart3 + t * RS_STRIDE;
    const int* nrs = nodestart3 + t * NRS_STRIDE;
    const float* dinv = dinv3 + t * N_NODES;
    int* dsrc = csrsrc3 + (size_t)t * E;
    float* dnorm = csrnorm3 + (size_t)t * E;
    int node = blockIdx.x * 4 + (threadIdx.x >> 6);
    int lane = threadIdx.x & 63;
    float din = dinv[node];
    int w = nrs[node];
#pragma unroll
    for (int p = 0; p < NPART; ++p) {
        int beg = prs[p * N_NODES + node];
        int end = prs[p * N_NODES + node + 1];
        for (int j = beg + lane; j < end; j += 64) {
            int2 c = src[j];
            dsrc[w + (j - beg)] = c.x;
            dnorm[w + (j - beg)] = __int_as_float(c.y) * dinv[c.x] * din;
        }
        w += end - beg;
    }
}

// ---------------------------------------------------------------------------
// Weight pre-pack: WT[n][k] = bf16(W[k][n]) for all 6 weights (grid.z = widx).
// ---------------------------------------------------------------------------
__global__ __launch_bounds__(256) void wpack_kernel(const float* __restrict__ w0,
                                                    const float* __restrict__ w1,
                                                    const float* __restrict__ w2,
                                                    const float* __restrict__ w3,
                                                    const float* __restrict__ w4,
                                                    const float* __restrict__ w5,
                                                    ushort* __restrict__ wt) {
    const float* W;
    switch (blockIdx.z) {
        case 0: W = w0; break; case 1: W = w1; break; case 2: W = w2; break;
        case 3: W = w3; break; case 4: W = w4; break; default: W = w5; break;
    }
    __shared__ float tl[16][17];
    int tx = threadIdx.x & 15, ty = threadIdx.x >> 4;
    int k0 = blockIdx.x * 16, n0 = blockIdx.y * 16;
    tl[ty][tx] = W[(size_t)(k0 + ty) * FM + n0 + tx];
    __syncthreads();
    wt[(size_t)blockIdx.z * FM * FM + (size_t)(n0 + ty) * FM + k0 + tx] = f2bf(tl[tx][ty]);
}

// x (fp32) -> bf16 once; reused as GEMM A input by the 3 first-layer convs.
__global__ void x2bf_kernel(const float* __restrict__ x, ushort* __restrict__ xb) {
    int i = blockIdx.x * blockDim.x + threadIdx.x;   // over NF/8
    if (i >= NF / 8) return;
    const float4* xp = (const float4*)x;
    float4 a = xp[2 * i], b = xp[2 * i + 1];
    uint4 pk;
    pk.x = pack2bf(a.x, a.y);
    pk.y = pack2bf(a.z, a.w);
    pk.z = pack2bf(b.x, b.y);
    pk.w = pack2bf(b.z, b.w);
    ((uint4*)xb)[i] = pk;
}

// ---------------------------------------------------------------------------
// Batched bf16 MFMA GEMM (grid.z = branch z in {f,s,g}):
//   A = A_base + z*a_stride  (layer1: xb stride 0; layer2: br_u stride 2*NF)
//   WT index = 2*z + layer   (weight order f1,f2,s1,s2,g1,g2)
//   C = C_base + z*NF
// BM=128, BN=64, BK=64; 4 waves (2x2); mfma_f32_16x16x32_bf16.
// ---------------------------------------------------------------------------
__global__ __launch_bounds__(256) void gemm_mfma_b(const ushort* __restrict__ A_base,
                                                   long a_stride,
                                                   const ushort* __restrict__ wt_base,
                                                   int layer,
                                                   ushort* __restrict__ C_base) {
    const int z = blockIdx.z;
    const ushort* A = A_base + (size_t)z * a_stride;
    const ushort* WT = wt_base + (size_t)(2 * z + layer) * (FM * FM);
    ushort* C = C_base + (size_t)z * NF;

    __shared__ ushort A_lds[128 * 64];

    const int tid = threadIdx.x;
    const int lane = tid & 63;
    const int wid = tid >> 6;
    const int wm = wid >> 1, wn = wid & 1;
    const int bm = blockIdx.x * 128;
    const int bn = blockIdx.y * 64;
    const int l15 = lane & 15;
    const int lg = lane >> 4;

    f32x4 acc[4][2];
#pragma unroll
    for (int i = 0; i < 4; ++i)
#pragma unroll
        for (int n = 0; n < 2; ++n) acc[i][n] = (f32x4){0.f, 0.f, 0.f, 0.f};

    const int srow = tid >> 1;
    const int shk = tid & 1;
    const ushort* arow_p = &A[(size_t)(bm + srow) * FM + shk * 32];

    for (int k0 = 0; k0 < 256; k0 += 64) {
        {
            const ushort* ap = arow_p + k0;
#pragma unroll
            for (int g = 0; g < 4; ++g) {
                ushort8 v = *(const ushort8*)(ap + g * 8);
                int kk = shk * 32 + g * 8;
                int idx = srow * 64 + (kk ^ ((srow & 7) << 3));
                *(ushort8*)&A_lds[idx] = v;
            }
        }
        __syncthreads();
#pragma unroll
        for (int s = 0; s < 2; ++s) {
            short8 bfrag[2];
#pragma unroll
            for (int n = 0; n < 2; ++n) {
                int col = bn + wn * 32 + n * 16 + l15;
                bfrag[n] = *(const short8*)&WT[(size_t)col * FM + k0 + s * 32 + lg * 8];
            }
#pragma unroll
            for (int i = 0; i < 4; ++i) {
                int row = wm * 64 + i * 16 + l15;
                int kk = s * 32 + lg * 8;
                short8 afrag = *(const short8*)&A_lds[row * 64 + (kk ^ ((row & 7) << 3))];
#pragma unroll
                for (int n = 0; n < 2; ++n)
                    acc[i][n] = __builtin_amdgcn_mfma_f32_16x16x32_bf16(
                        afrag, bfrag[n], acc[i][n], 0, 0, 0);
            }
        }
        __syncthreads();
    }
#pragma unroll
    for (int i = 0; i < 4; ++i) {
#pragma unroll
        for (int n = 0; n < 2; ++n) {
            int col = bn + wn * 32 + n * 16 + l15;
#pragma unroll
            for (int r = 0; r < 4; ++r) {
                int row = bm + wm * 64 + i * 16 + lg * 4 + r;
                C[(size_t)row * FM + col] = f2bf(acc[i][n][r]);
            }
        }
    }
}

// ---------------------------------------------------------------------------
// Fused GCN aggregation: CSR gather over bf16 h -> bf16 branch out.
// No pooled-sum fusion (r19 lesson). One wave per node; unroll-4, 2 chains.
// out[d][:] = relu( b + dinv[d]^2*h[d][:] + sum_j norm_j*h[src_j][:] )
// ---------------------------------------------------------------------------
__global__ __launch_bounds__(256) void gcn_aggregate_csr(const ushort* __restrict__ h,
                                                         const int* __restrict__ row_start,
                                                         const int* __restrict__ csr_src,
                                                         const float* __restrict__ csr_norm,
                                                         const float* __restrict__ dinv,
                                                         const float* __restrict__ bias,
                                                         ushort* __restrict__ out) {
    int node = blockIdx.x * 4 + (threadIdx.x >> 6);
    int lane = threadIdx.x & 63;
    const ushort4* hp = (const ushort4*)h;

    float di = dinv[node];
    float sw = di * di;
    ushort4 q = hp[(size_t)node * 64 + lane];
    float4 accA = make_float4(bf2f(q.x) * sw, bf2f(q.y) * sw,
                              bf2f(q.z) * sw, bf2f(q.w) * sw);
    float4 accB = make_float4(0.f, 0.f, 0.f, 0.f);

    int beg = row_start[node];
    int end = row_start[node + 1];
    int j = beg;
    for (; j + 3 < end; j += 4) {
        int s0 = csr_src[j];
        int s1 = csr_src[j + 1];
        int s2 = csr_src[j + 2];
        int s3 = csr_src[j + 3];
        float w0 = csr_norm[j];
        float w1 = csr_norm[j + 1];
        float w2 = csr_norm[j + 2];
        float w3 = csr_norm[j + 3];
        ushort4 q0 = hp[(size_t)s0 * 64 + lane];
        ushort4 q1 = hp[(size_t)s1 * 64 + lane];
        ushort4 q2 = hp[(size_t)s2 * 64 + lane];
        ushort4 q3 = hp[(size_t)s3 * 64 + lane];
        accA.x += w0 * bf2f(q0.x) + w1 * bf2f(q1.x);
        accA.y += w0 * bf2f(q0.y) + w1 * bf2f(q1.y);
        accA.z += w0 * bf2f(q0.z) + w1 * bf2f(q1.z);
        accA.w += w0 * bf2f(q0.w) + w1 * bf2f(q1.w);
        accB.x += w2 * bf2f(q2.x) + w3 * bf2f(q3.x);
        accB.y += w2 * bf2f(q2.y) + w3 * bf2f(q3.y);
        accB.z += w2 * bf2f(q2.z) + w3 * bf2f(q3.z);
        accB.w += w2 * bf2f(q2.w) + w3 * bf2f(q3.w);
    }
    for (; j < end; ++j) {
        int s0 = csr_src[j];
        float w0 = csr_norm[j];
        ushort4 q0 = hp[(size_t)s0 * 64 + lane];
        accA.x += w0 * bf2f(q0.x);
        accA.y += w0 * bf2f(q0.y);
        accA.z += w0 * bf2f(q0.z);
        accA.w += w0 * bf2f(q0.w);
    }
    float4 bb = ((const float4*)bias)[lane];
    float4 r;
    r.x = fmaxf(accA.x + accB.x + bb.x, 0.0f);
    r.y = fmaxf(accA.y + accB.y + bb.y, 0.0f);
    r.z = fmaxf(accA.z + accB.z + bb.z, 0.0f);
    r.w = fmaxf(accA.w + accB.w + bb.w, 0.0f);
    ushort4 o;
    o.x = f2bf(r.x); o.y = f2bf(r.y); o.z = f2bf(r.z); o.w = f2bf(r.w);
    ((ushort4*)out)[(size_t)node * 64 + lane] = o;
}

// ---------------------------------------------------------------------------
// SE attention: separate branch reduction over bf16 branch tensors.
// ---------------------------------------------------------------------------
__global__ __launch_bounds__(256) void reduce_branch_kernel(const ushort* __restrict__ br,
                                                            float* __restrict__ pooled) {
    int c = blockIdx.y;
    const ushort8* p = (const ushort8*)(br + (size_t)c * NF + (size_t)blockIdx.x * 16384);
    float s = 0.0f;
#pragma unroll
    for (int i = 0; i < 8; ++i) {
        ushort8 v = p[threadIdx.x + i * 256];
#pragma unroll
        for (int k = 0; k < 8; ++k) s += bf2f(v[k]);
    }
    for (int o = 32; o > 0; o >>= 1) s += __shfl_down(s, o);
    __shared__ float wsum[4];
    if ((threadIdx.x & 63) == 0) wsum[threadIdx.x >> 6] = s;
    __syncthreads();
    if (threadIdx.x == 0)
        atomicAdd(&pooled[c], wsum[0] + wsum[1] + wsum[2] + wsum[3]);
}

__global__ void se_kernel(const float* __restrict__ pooled_sum,
                          const float* __restrict__ fc1_w, const float* __restrict__ fc1_b,
                          const float* __restrict__ fc2_w, const float* __restrict__ fc2_b,
                          float* __restrict__ att) {
    __shared__ float p[6];
    __shared__ float hbuf[30];
    int t = threadIdx.x;
    if (t < 6) p[t] = pooled_sum[t] * (1.0f / ((float)N_NODES * (float)FM));
    __syncthreads();
    if (t < 30) {
        float a = fc1_b[t];
#pragma unroll
        for (int c = 0; c < 6; ++c) a += fc1_w[t * 6 + c] * p[c];
        hbuf[t] = fmaxf(a, 0.0f);
    }
    __syncthreads();
    if (t < 6) {
        float a = fc2_b[t];
#pragma unroll
        for (int j = 0; j < 30; ++j) a += fc2_w[t * 30 + j] * hbuf[j];
        att[t] = 1.0f / (1.0f + expf(-a));
    }
}

// out[n][f] = sum_c cnn_w[c] * relu(att[c] * br_c[n][f]) + cnn_b  (br bf16)
__global__ void combine_kernel(const ushort* __restrict__ br,
                               const float* __restrict__ att,
                               const float* __restrict__ cnn_w,
                               const float* __restrict__ cnn_b,
                               float* __restrict__ out, int total4) {
    int i = blockIdx.x * blockDim.x + threadIdx.x;
    if (i >= total4) return;
    float a[6], w[6];
#pragma unroll
    for (int c = 0; c < 6; ++c) { a[c] = att[c]; w[c] = cnn_w[c]; }
    float cb = cnn_b[0];
    float4 acc = make_float4(cb, cb, cb, cb);
#pragma unroll
    for (int c = 0; c < 6; ++c) {
        ushort4 q = ((const ushort4*)(br + (size_t)c * NF))[i];
        acc.x += w[c] * fmaxf(a[c] * bf2f(q.x), 0.0f);
        acc.y += w[c] * fmaxf(a[c] * bf2f(q.y), 0.0f);
        acc.z += w[c] * fmaxf(a[c] * bf2f(q.z), 0.0f);
        acc.w += w[c] * fmaxf(a[c] * bf2f(q.w), 0.0f);
    }
    ((float4*)out)[i] = acc;
}

// ---------------------------------------------------------------------------
// Host orchestration
// ---------------------------------------------------------------------------

extern "C" void kernel_launch(void* const* d_in, const int* in_sizes, int n_in,
                              void* d_out, int out_size, void* d_ws, size_t ws_size,
                              hipStream_t stream) {
    const float* x      = (const float*)d_in[0];
    const int*   ed_f   = (const int*)d_in[1];
    const float* ew_f   = (const float*)d_in[2];
    const int*   ed_s   = (const int*)d_in[3];
    const float* ew_s   = (const float*)d_in[4];
    const int*   ed_g   = (const int*)d_in[5];
    const float* ew_g   = (const float*)d_in[6];
    const float* Wf1 = (const float*)d_in[7];  const float* bf1 = (const float*)d_in[8];
    const float* Wf2 = (const float*)d_in[9];  const float* bf2 = (const float*)d_in[10];
    const float* Ws1 = (const float*)d_in[11]; const float* bs1 = (const float*)d_in[12];
    const float* Ws2 = (const float*)d_in[13]; const float* bs2 = (const float*)d_in[14];
    const float* Wg1 = (const float*)d_in[15]; const float* bg1 = (const float*)d_in[16];
    const float* Wg2 = (const float*)d_in[17]; const float* bg2 = (const float*)d_in[18];
    const float* fc1_w = (const float*)d_in[19]; const float* fc1_b = (const float*)d_in[20];
    const float* fc2_w = (const float*)d_in[21]; const float* fc2_b = (const float*)d_in[22];
    const float* cnn_w = (const float*)d_in[23]; const float* cnn_b = (const float*)d_in[24];

    const int E = in_sizes[1] / 2;   // 524288

    // Workspace layout:
    ushort* br_u = (ushort*)d_ws;                      // 6*NF bf16 branch outputs
    ushort* xb   = br_u + (size_t)6 * NF;              // NF bf16 (x converted)
    ushort* h3   = xb + NF;                            // 3*NF bf16 (batched h)
    ushort* wt   = h3 + (size_t)3 * NF;                // 6*FM*FM bf16 (WT packed)
    float*  dinv3  = (float*)(wt + 6 * FM * FM);       // 3*N_NODES
    float*  pooled = dinv3 + 3 * N_NODES;              // 8
    float*  att    = pooled + 8;                       // 8
    int*    cnt3       = (int*)(att + 8);              // 3*NSCAN
    int*    cursor3    = cnt3 + 3 * NSCAN;             // 3*NSCAN
    int*    rowstart3  = cursor3 + 3 * NSCAN;          // 3*RS_STRIDE
    int*    nodestart3 = rowstart3 + 3 * RS_STRIDE;    // 3*NRS_STRIDE
    int*    tot3       = nodestart3 + 3 * NRS_STRIDE + 2;  // 3*N_NODES
    int*    psum       = tot3 + 3 * N_NODES;           // 3*NCHUNK
    int*    npsum      = psum + 3 * NCHUNK;            // 3*NCHUNK_N (+pad)
    int2*   csr3       = (int2*)(npsum + 3 * NCHUNK_N + 8);  // 3*E int2 (partitioned)
    int*    csr_src3   = (int*)(csr3 + (size_t)3 * E); // 3*E int (contiguous)
    float*  csr_norm3  = (float*)(csr_src3 + (size_t)3 * E);  // 3*E float

    float* dinv_set[3] = { dinv3, dinv3 + N_NODES, dinv3 + 2 * N_NODES };
    int*   nrs_set[3]  = { nodestart3, nodestart3 + NRS_STRIDE,
                           nodestart3 + 2 * NRS_STRIDE };
    int*   csrc_set[3] = { csr_src3, csr_src3 + E, csr_src3 + 2 * E };
    float* cnorm_set[3] = { csr_norm3, csr_norm3 + E, csr_norm3 + 2 * E };
    const float* b1_set[3] = { bf1, bs1, bg1 };
    const float* b2_set[3] = { bf2, bs2, bg2 };

    // --- partitioned CSR build with parallel hierarchical scans ---
    init_kernel<<<(3 * NSCAN + 6 + 255) / 256, 256, 0, stream>>>(cnt3, pooled);
    {
        dim3 g((E + 255) / 256, 3);
        cnt_edges_all<<<g, 256, 0, stream>>>(ed_f + E, ed_s + E, ed_g + E, cnt3, E);
    }
    tot_kernel<<<(3 * N_NODES + 255) / 256, 256, 0, stream>>>(cnt3, tot3);
    {
        dim3 g1d(NCHUNK, 3);
        chunk_sum<<<g1d, 1024, 0, stream>>>(cnt3, (long)NSCAN, psum, NCHUNK);
        dim3 g2d(NCHUNK_N, 3);
        chunk_sum<<<g2d, 1024, 0, stream>>>(tot3, (long)N_NODES, npsum, NCHUNK_N);
    }
    scan_chunks<<<1, 128, 0, stream>>>(psum, npsum);
    {
        dim3 g1d(NCHUNK, 3);
        scan_write_rs<<<g1d, 1024, 0, stream>>>(cnt3, psum, rowstart3, cursor3);
        dim3 g2d(NCHUNK_N, 3);
        scan_write_nrs<<<g2d, 1024, 0, stream>>>(tot3, npsum, nodestart3);
    }
    {
        dim3 g((E + 255) / 256, 3);
        scatter_all<<<g, 256, 0, stream>>>(ed_f, ed_s, ed_g, ew_f, ew_s, ew_g,
                                           cursor3, csr3, E);
    }
    {
        dim3 g(N_NODES / 4, 3);
        deg_dinv_all<<<g, 256, 0, stream>>>(csr3, rowstart3, dinv3, E);
    }
    {
        dim3 g(N_NODES / 4, 3);
        compact_norm_all<<<g, 256, 0, stream>>>(csr3, rowstart3, nodestart3, dinv3,
                                                csr_src3, csr_norm3, E);
    }
    // --- weight pre-pack + x conversion ---
    {
        dim3 wg(16, 16, 6);
        wpack_kernel<<<wg, 256, 0, stream>>>(Wf1, Wf2, Ws1, Ws2, Wg1, Wg2, wt);
    }
    x2bf_kernel<<<(NF / 8 + 255) / 256, 256, 0, stream>>>(x, xb);

    // --- layer 1: one batched GEMM, then 3 per-branch aggs ---
    {
        dim3 gg(N_NODES / 128, FM / 64, 3);
        gemm_mfma_b<<<gg, 256, 0, stream>>>(xb, 0L, wt, 0, h3);
        for (int z = 0; z < 3; ++z)
            gcn_aggregate_csr<<<N_NODES / 4, 256, 0, stream>>>(
                h3 + (size_t)z * NF, nrs_set[z], csrc_set[z], cnorm_set[z],
                dinv_set[z], b1_set[z], br_u + (size_t)(2 * z) * NF);
    }
    // --- layer 2 ---
    {
        dim3 gg(N_NODES / 128, FM / 64, 3);
        gemm_mfma_b<<<gg, 256, 0, stream>>>(br_u, (long)(2 * (size_t)NF), wt, 1, h3);
        for (int z = 0; z < 3; ++z)
            gcn_aggregate_csr<<<N_NODES / 4, 256, 0, stream>>>(
                h3 + (size_t)z * NF, nrs_set[z], csrc_set[z], cnorm_set[z],
                dinv_set[z], b2_set[z], br_u + (size_t)(2 * z + 1) * NF);
    }

    // --- SE attention ---
    {
        dim3 rgrid(256, 6);
        reduce_branch_kernel<<<rgrid, 256, 0, stream>>>(br_u, pooled);
    }
    se_kernel<<<1, 64, 0, stream>>>(pooled, fc1_w, fc1_b, fc2_w, fc2_b, att);

    // --- final 1x1 conv combine ---
    combine_kernel<<<NF4 / 256, 256, 0, stream>>>(br_u, att, cnn_w, cnn_b,
                                                  (float*)d_out, NF4);
}